// Round 7
// baseline (460.838 us; speedup 1.0000x reference)
//
#include <hip/hip_runtime.h>

// Spiking NN collapses to 3 dependent masked binary matvecs (input drive is
// nonzero only at t=0; decaying membranes can never re-cross threshold):
//   enc = (u < x);  s0 = (W0*M0)@enc > 1;  s1 = (W1*M1)@s0 > 1;
//   out = ((W2*M2)@s1 > 1) ? 1/time_steps : 0
// v8: v0/v5/v6/v7 (four distinct memory paths) all land at wall 343-346 us
// => our kernels total ~110 us (~3.5 TB/s) hidden under the harness's 58 us
// re-poison fills -- never visible in top-5 counters. Fuse the three
// v7-style LDS-DMA phases into ONE dispatch with the v3-proven manual grid
// barrier: viable now because global_load_lds needs no dest VGPRs (v4's
// spill mechanism is gone). 512 blocks x 64.6 KB LDS = exactly 2
// blocks/CU, all co-resident (barrier deadlock-free). Kills 2 dispatch
// ramps/tails AND makes the kernel big enough to surface in top-5 with
// full counters either way.

constexpr int N = 4096;
constexpr int NBLOCKS = 512;
typedef float f32x4 __attribute__((ext_vector_type(4)));

#define GLOBAL_AS __attribute__((address_space(1)))
#define LDS_AS    __attribute__((address_space(3)))

// ---------- encoder: 4096 bits of (u < x) via ballot ----------
__global__ __launch_bounds__(256) void enc_kernel(
    const float* __restrict__ x, const float* __restrict__ u,
    unsigned long long* __restrict__ emask)
{
    const int j = blockIdx.x * 256 + threadIdx.x;
    const unsigned long long b = __ballot(u[j] < x[j]);
    if ((threadIdx.x & 63) == 0) emask[j >> 6] = b;
}

// v3-proven manual grid barrier (all blocks co-resident by construction).
__device__ __forceinline__ void grid_barrier(int* cnt)
{
    __syncthreads();                       // drains this block's stores
    if (threadIdx.x == 0) {
        __threadfence();                   // release: L2 writeback (agent)
        atomicAdd(cnt, 1);                 // device-scope RMW
        while (__hip_atomic_load(cnt, __ATOMIC_RELAXED,
                                 __HIP_MEMORY_SCOPE_AGENT) < NBLOCKS)
            __builtin_amdgcn_s_sleep(2);
        __threadfence();                   // acquire: invalidate stale caches
    }
    __syncthreads();
}

__device__ __forceinline__ void issue_chunk(
    const f32x4* __restrict__ Wrow, const f32x4* __restrict__ Mrow,
    int c, f32x4* ldsW, f32x4* ldsM, int lane)
{
#pragma unroll
    for (int i = 0; i < 4; ++i) {
        __builtin_amdgcn_global_load_lds(
            (const GLOBAL_AS void*)&Wrow[c * 256 + i * 64 + lane],
            (LDS_AS void*)&ldsW[i * 64], 16, 0, 0);
        __builtin_amdgcn_global_load_lds(
            (const GLOBAL_AS void*)&Mrow[c * 256 + i * 64 + lane],
            (LDS_AS void*)&ldsM[i * 64], 16, 0, 0);
    }
}

// One layer phase: mask -> LDS, sync (vmcnt drains to 0), 16-DMA prologue,
// 8 steps with counted vmcnt(8) waits (v7's verified bookkeeping).
template <bool FINAL>
__device__ __forceinline__ void snn_phase(
    const float* __restrict__ W, const float* __restrict__ Mk,
    const unsigned int* __restrict__ in_mask,   // 128 words = 4096 col bits
    unsigned char* __restrict__ out_mask,       // 512 B (if !FINAL)
    const int* __restrict__ t_steps, float* __restrict__ out,
    f32x4* sWb, f32x4* sMb, unsigned int* smaskw, int* sbits,
    int lane, int wave, int row0)
{
    if (threadIdx.x < 128) smaskw[threadIdx.x] = in_mask[threadIdx.x];
    __syncthreads();                       // mask in LDS; vmcnt == 0 after
    const unsigned char* smb = (const unsigned char*)smaskw;

    const int row1 = row0 + 1;
    const f32x4* Wr0 = reinterpret_cast<const f32x4*>(W  + (size_t)row0 * N);
    const f32x4* Wr1 = reinterpret_cast<const f32x4*>(W  + (size_t)row1 * N);
    const f32x4* Mr0 = reinterpret_cast<const f32x4*>(Mk + (size_t)row0 * N);
    const f32x4* Mr1 = reinterpret_cast<const f32x4*>(Mk + (size_t)row1 * N);

    // Prologue: 16 DMA ops in flight.
    issue_chunk(Wr0, Mr0, 0, sWb,       sMb,       lane);
    issue_chunk(Wr0, Mr0, 1, sWb + 256, sMb + 256, lane);

    double a0 = 0, a1 = 0, a2 = 0, a3 = 0;
    double b0 = 0, b1 = 0, b2 = 0, b3 = 0;

#define STEP(K, WN)                                                            \
    do {                                                                       \
        asm volatile("s_waitcnt vmcnt(" WN ")" ::: "memory");                  \
        __builtin_amdgcn_sched_barrier(0);                                     \
        const int c = (K) & 3;                                                 \
        const f32x4* bw = sWb + ((K) & 1) * 256;                               \
        const f32x4* bm = sMb + ((K) & 1) * 256;                               \
        f32x4 w[4], m[4];                                                      \
        unsigned int nb[4];                                                    \
        _Pragma("unroll")                                                      \
        for (int i = 0; i < 4; ++i) {                                          \
            w[i] = bw[i * 64 + lane];                                          \
            m[i] = bm[i * 64 + lane];                                          \
            const int idx = c * 256 + i * 64 + lane;                           \
            nb[i] = ((unsigned int)smb[idx >> 1] >> ((idx & 1) * 4)) & 0xFu;   \
        }                                                                      \
        asm volatile("s_waitcnt lgkmcnt(0)" ::: "memory");                     \
        __builtin_amdgcn_sched_barrier(0);                                     \
        if ((K) + 2 < 8)                                                       \
            issue_chunk(((K) + 2 < 4) ? Wr0 : Wr1, ((K) + 2 < 4) ? Mr0 : Mr1,  \
                        ((K) + 2) & 3, sWb + ((K) & 1) * 256,                  \
                        sMb + ((K) & 1) * 256, lane);                          \
        double& r0 = ((K) < 4) ? a0 : b0;                                      \
        double& r1 = ((K) < 4) ? a1 : b1;                                      \
        double& r2 = ((K) < 4) ? a2 : b2;                                      \
        double& r3 = ((K) < 4) ? a3 : b3;                                      \
        _Pragma("unroll")                                                      \
        for (int i = 0; i < 4; ++i) {                                          \
            r0 = fma((double)w[i].x, (double)((nb[i] & 1u) ? m[i].x : 0.0f), r0); \
            r1 = fma((double)w[i].y, (double)((nb[i] & 2u) ? m[i].y : 0.0f), r1); \
            r2 = fma((double)w[i].z, (double)((nb[i] & 4u) ? m[i].z : 0.0f), r2); \
            r3 = fma((double)w[i].w, (double)((nb[i] & 8u) ? m[i].w : 0.0f), r3); \
        }                                                                      \
    } while (0)

    STEP(0, "8"); STEP(1, "8"); STEP(2, "8"); STEP(3, "8");
    STEP(4, "8"); STEP(5, "8"); STEP(6, "8"); STEP(7, "0");
#undef STEP

    double t0 = (a0 + a1) + (a2 + a3);
    double t1 = (b0 + b1) + (b2 + b3);
#pragma unroll
    for (int off = 32; off > 0; off >>= 1) {
        t0 += __shfl_down(t0, off, 64);
        t1 += __shfl_down(t1, off, 64);
    }

    if (FINAL) {
        if (lane == 0) {
            const float sc = 1.0f / (float)t_steps[0];
            out[row0] = (t0 > 1.0) ? sc : 0.0f;
            out[row1] = (t1 > 1.0) ? sc : 0.0f;
        }
    } else {
        if (lane == 0) {
            sbits[2 * wave]     = (t0 > 1.0) ? 1 : 0;
            sbits[2 * wave + 1] = (t1 > 1.0) ? 1 : 0;
        }
        __syncthreads();
        if (threadIdx.x == 0) {
            unsigned int byte = 0;
#pragma unroll
            for (int i = 0; i < 8; ++i) byte |= (unsigned int)sbits[i] << i;
            out_mask[blockIdx.x] = (unsigned char)byte;
        }
    }
}

// 512 blocks x 256 threads; LDS 64.6 KB -> exactly 2 blocks/CU, all 512
// co-resident (LDS-limited). launch_bounds(256,2) = 2 waves/EU = 8
// waves/CU, VGPR cap 256 (no pressure: loads land in LDS, not VGPRs).
__global__ __launch_bounds__(256, 2) void snn_fused(
    const float* __restrict__ W0, const float* __restrict__ W1,
    const float* __restrict__ W2, const float* __restrict__ M0,
    const float* __restrict__ M1, const float* __restrict__ M2,
    const unsigned int* __restrict__ emask,
    unsigned char* __restrict__ m0, unsigned char* __restrict__ m1,
    const int* __restrict__ t_steps, float* __restrict__ out, int* bar)
{
    const int lane = threadIdx.x & 63;
    const int wave = threadIdx.x >> 6;
    const int row0 = blockIdx.x * 8 + wave * 2;   // block owns 8 rows

    __shared__ f32x4 sW[4][2][256];               // 32 KB
    __shared__ f32x4 sM[4][2][256];               // 32 KB
    __shared__ unsigned int smaskw[128];
    __shared__ int sbits[8];

    snn_phase<false>(W0, M0, emask, m0, nullptr, nullptr,
                     &sW[wave][0][0], &sM[wave][0][0], smaskw, sbits,
                     lane, wave, row0);
    grid_barrier(bar);
    snn_phase<false>(W1, M1, (const unsigned int*)m0, m1, nullptr, nullptr,
                     &sW[wave][0][0], &sM[wave][0][0], smaskw, sbits,
                     lane, wave, row0);
    grid_barrier(bar + 64);
    snn_phase<true>(W2, M2, (const unsigned int*)m1, nullptr, t_steps, out,
                    &sW[wave][0][0], &sM[wave][0][0], smaskw, sbits,
                    lane, wave, row0);
}

extern "C" void kernel_launch(void* const* d_in, const int* in_sizes, int n_in,
                              void* d_out, int out_size, void* d_ws, size_t ws_size,
                              hipStream_t stream)
{
    const float* x  = (const float*)d_in[0];
    const float* u  = (const float*)d_in[1];
    const float* W0 = (const float*)d_in[2];
    const float* W1 = (const float*)d_in[3];
    const float* W2 = (const float*)d_in[4];
    const float* M0 = (const float*)d_in[5];
    const float* M1 = (const float*)d_in[6];
    const float* M2 = (const float*)d_in[7];
    const int* t_steps = (const int*)d_in[8];
    float* out = (float*)d_out;

    // ws: emask 512 B | m0 512 B | m1 512 B | barrier counters.
    // Masks are fully rewritten before being read each call (poison-safe);
    // barrier counters re-zeroed by a capture-legal stream memset.
    unsigned long long* emask = (unsigned long long*)d_ws;
    unsigned char* m0 = (unsigned char*)d_ws + 512;
    unsigned char* m1 = (unsigned char*)d_ws + 1024;
    int* bar = (int*)((unsigned char*)d_ws + 2048);

    hipMemsetAsync(bar, 0, 128 * sizeof(int), stream);

    enc_kernel<<<dim3(16), dim3(256), 0, stream>>>(x, u, emask);
    snn_fused<<<dim3(NBLOCKS), dim3(256), 0, stream>>>(
        W0, W1, W2, M0, M1, M2, (const unsigned int*)emask,
        m0, m1, t_steps, out, bar);
}

// Round 8
// 342.765 us; speedup vs baseline: 1.3445x; 1.3445x over previous
//
#include <hip/hip_runtime.h>

// Spiking NN collapses to 3 dependent masked binary matvecs (input drive is
// nonzero only at t=0; decaying membranes can never re-cross threshold):
//   enc = (u < x);  s0 = (W0*M0)@enc > 1;  s1 = (W1*M1)@s0 > 1;
//   out = ((W2*M2)@s1 > 1) ? 1/time_steps : 0
// HBM-bound: 384 MB of W+M streamed once per call. v9: all 3-dispatch
// variants (VGPR-direct, 2-wave/row, LDS-DMA burst, LDS-DMA pipelined) hit
// exactly ~3.5 TB/s despite in-flight bytes >= 2x the Little's-law need ->
// bandwidth ceiling of the PATTERN, not latency. Suspect: all waves march
// chunk 0,1,2,... in lockstep over rows strided 16 KB, so the grid's
// requests stay congruent mod 16 KB and concentrate on a rotating channel
// subset (fills, thread-linear, blanket all channels -> 6.9 TB/s).
// Single change vs v5: rotate each wave's chunk order by a per-(row,half)
// phase so leading edges cover all 16 KB-period phases uniformly.
// f64 sum order is permuted only (each product exact; compare margin huge).

constexpr int N = 4096;
typedef float f32x4 __attribute__((ext_vector_type(4)));

template <bool ENCODE, bool FINAL>
__global__ __launch_bounds__(256) void snn_layer(
    const float* __restrict__ W, const float* __restrict__ Mk,
    const float* __restrict__ S, const float* __restrict__ U,
    const int* __restrict__ t_steps, float* __restrict__ out)
{
    const int lane = threadIdx.x & 63;
    const int wave = threadIdx.x >> 6;
    const int row  = (blockIdx.x << 1) | (wave >> 1);   // 2 rows per block
    const int half = wave & 1;                          // 2 waves per row

    const f32x4* W4 = reinterpret_cast<const f32x4*>(W + (size_t)row * N);
    const f32x4* M4 = reinterpret_cast<const f32x4*>(Mk + (size_t)row * N);
    const f32x4* S4 = reinterpret_cast<const f32x4*>(S);
    const f32x4* U4 = reinterpret_cast<const f32x4*>(U);

    const int base  = half * (N / 8);                   // f32x4 offset: 0 or 512
    const int phase = ((row << 1) | half) & 7;          // chunk-order rotation

    // 4 independent f64 chains over 8 chunks, fully unrolled; chunk order
    // rotated per wave to decorrelate the grid's instantaneous addresses.
    double a0 = 0.0, a1 = 0.0, a2 = 0.0, a3 = 0.0;
#pragma unroll
    for (int it = 0; it < N / 8 / 64; ++it) {           // 8 iterations
        const int c   = (it + phase) & 7;               // rotated chunk index
        const int idx = base + c * 64 + lane;           // coalesced 1 KB/wave
        f32x4 w = W4[idx];
        f32x4 m = M4[idx];
        f32x4 s = S4[idx];                              // hot in L1/L2 (16 KB)
        if (ENCODE) {
            f32x4 uu = U4[idx];
            s.x = (uu.x < s.x) ? 1.0f : 0.0f;
            s.y = (uu.y < s.y) ? 1.0f : 0.0f;
            s.z = (uu.z < s.z) ? 1.0f : 0.0f;
            s.w = (uu.w < s.w) ? 1.0f : 0.0f;
        }
        // m and s are exact {0,1}; w*(m*s) is exact in f64 -> near-exact sum
        a0 = fma((double)w.x, (double)(m.x * s.x), a0);
        a1 = fma((double)w.y, (double)(m.y * s.y), a1);
        a2 = fma((double)w.z, (double)(m.z * s.z), a2);
        a3 = fma((double)w.w, (double)(m.w * s.w), a3);
    }
    double acc = (a0 + a1) + (a2 + a3);
#pragma unroll
    for (int off = 32; off > 0; off >>= 1)
        acc += __shfl_down(acc, off, 64);

    // Combine the two half-row partials per row through LDS.
    __shared__ double part[4];
    if (lane == 0) part[wave] = acc;
    __syncthreads();

    if (lane == 0 && half == 0) {
        const double tot = part[wave] + part[wave | 1];
        if (FINAL) {
            out[row] = (tot > 1.0) ? (1.0f / (float)t_steps[0]) : 0.0f;
        } else {
            out[row] = (tot > 1.0) ? 1.0f : 0.0f;
        }
    }
}

extern "C" void kernel_launch(void* const* d_in, const int* in_sizes, int n_in,
                              void* d_out, int out_size, void* d_ws, size_t ws_size,
                              hipStream_t stream)
{
    const float* x  = (const float*)d_in[0];
    const float* u  = (const float*)d_in[1];
    const float* W0 = (const float*)d_in[2];
    const float* W1 = (const float*)d_in[3];
    const float* W2 = (const float*)d_in[4];
    const float* M0 = (const float*)d_in[5];
    const float* M1 = (const float*)d_in[6];
    const float* M2 = (const float*)d_in[7];
    const int* t_steps = (const int*)d_in[8];
    float* out = (float*)d_out;

    float* s0 = (float*)d_ws;       // 4096 floats, fully rewritten each call
    float* s1 = s0 + N;             // 4096 floats

    dim3 grid(N / 2), block(256);   // 2048 blocks: 2 rows/block, 2 waves/row
    snn_layer<true,  false><<<grid, block, 0, stream>>>(W0, M0, x,  u,       nullptr, s0);
    snn_layer<false, false><<<grid, block, 0, stream>>>(W1, M1, s0, nullptr, nullptr, s1);
    snn_layer<false, true ><<<grid, block, 0, stream>>>(W2, M2, s1, nullptr, t_steps, out);
}